// Round 18
// baseline (149.420 us; speedup 1.0000x reference)
//
#include <hip/hip_runtime.h>
#include <math.h>

#define B 8
#define D 512
#define N 4096
#define HEADS 8
#define DH 64
#define HID 512
#define O3 1536
#define KDIM 512
#define SCALE 0.125f
#define SQRT_D 22.62741699796952f

typedef __attribute__((ext_vector_type(4))) float f32x4;
typedef __attribute__((ext_vector_type(8))) short bf16x8;

static __device__ __forceinline__ unsigned short f2bf(float f) {
    unsigned int u = __float_as_uint(f);
    unsigned int r = (u + 0x7fffu + ((u >> 16) & 1u)) >> 16;
    return (unsigned short)r;
}

static __device__ __forceinline__ float bf2f(unsigned short u) {
    return __uint_as_float((unsigned int)u << 16);
}

static __device__ __forceinline__ void gload_lds16(const void* g, void* l) {
    __builtin_amdgcn_global_load_lds(
        (const __attribute__((address_space(1))) unsigned int*)g,
        (__attribute__((address_space(3))) unsigned int*)l, 16, 0, 0);
}

// ---------------------------------------------------------------------------
// prep: fused cvt_w + transpose_x.
// grid (96, 8, 9): z<8 & x<64 -> transpose x[b]; z==8 -> cvt w_qkv.
// ---------------------------------------------------------------------------
__global__ __launch_bounds__(256) void prep(const float* __restrict__ x,
                                            unsigned short* __restrict__ xT,
                                            const float* __restrict__ w,
                                            unsigned short* __restrict__ wb) {
    if (blockIdx.z == B) {
        int i = ((blockIdx.y * 96 + blockIdx.x) * 256 + threadIdx.x) * 4;
        float4 v = *(const float4*)(w + i);
        __align__(8) unsigned short o[4] = {f2bf(v.x), f2bf(v.y), f2bf(v.z), f2bf(v.w)};
        *(uint2*)(wb + i) = *(const uint2*)o;
        return;
    }
    if (blockIdx.x >= 64) return;
    __shared__ float tile[64][65];
    const int n0 = blockIdx.x * 64, d0 = blockIdx.y * 64, b = blockIdx.z;
    const float* xb = x + (size_t)b * D * N;
    unsigned short* xTb = xT + (size_t)b * N * KDIM;
    const int t = threadIdx.x;
    const int r = t >> 4, c4 = (t & 15) * 4;
#pragma unroll
    for (int i = 0; i < 4; ++i) {
        int row = r + i * 16;
        float4 v = *(const float4*)(xb + (size_t)(d0 + row) * N + n0 + c4);
        tile[row][c4 + 0] = v.x;
        tile[row][c4 + 1] = v.y;
        tile[row][c4 + 2] = v.z;
        tile[row][c4 + 3] = v.w;
    }
    __syncthreads();
#pragma unroll
    for (int pass = 0; pass < 2; ++pass) {
        int orow = (t >> 3) + pass * 32;
        int oc = (t & 7) * 8;
        __align__(16) unsigned short o[8];
#pragma unroll
        for (int e = 0; e < 8; ++e) o[e] = f2bf(tile[oc + e][orow]);
        *(uint4*)(xTb + (size_t)(n0 + orow) * KDIM + d0 + oc) = *(const uint4*)o;
    }
}

// ---------------------------------------------------------------------------
// 256x256 8-wave GEMM core (R13/R15, best race-free): full-tile prefetch,
// 2 barriers/K-tile, counted vmcnt(8), chunk-XOR swizzle both sides.
// No min-waves launch_bounds: acc[8][4]=128 VGPRs makes 2 blocks/CU
// impossible for this tile (R16 lesson: capping the allocator spills).
// ---------------------------------------------------------------------------
#define STAGE_H(PTR, REGION, TILE0, KT, H)                                         \
    _Pragma("unroll") for (int sub = 0; sub < 2; ++sub)                            \
        gload_lds16(PTR + (size_t)((TILE0) + (H) * 128 + spr[sub]) * KDIM          \
                        + (KT) * 64 + scoff[sub],                                  \
                    lds + (REGION) + ((KT) & 1) * 32768 + (H) * 16384              \
                        + sub * 8192 + t * 16);

#define PHASE_A(MG, KS)                                                            \
    _Pragma("unroll") for (int j = 0; j < 4; ++j)                                  \
        afr[j] = *(const bf16x8*)(lds + rbuf + arb + ((MG) * 4 + j) * 2048 + xa[KS]);

#define PHASE_B(KS)                                                               \
    _Pragma("unroll") for (int nf = 0; nf < 4; ++nf)                               \
        bfr[nf] = *(const bf16x8*)(lds + 65536 + rbuf + brb + nf * 2048 + xa[KS]);

#define PHASE_MMA(MG)                                                              \
    asm volatile("s_waitcnt lgkmcnt(0)" ::: "memory");                             \
    __builtin_amdgcn_sched_barrier(0);                                             \
    __builtin_amdgcn_s_setprio(1);                                                 \
    _Pragma("unroll") for (int j = 0; j < 4; ++j)                                  \
        _Pragma("unroll") for (int nf = 0; nf < 4; ++nf)                           \
            acc[(MG) * 4 + j][nf] = __builtin_amdgcn_mfma_f32_16x16x32_bf16(       \
                afr[j], bfr[nf], acc[(MG) * 4 + j][nf], 0, 0, 0);                  \
    __builtin_amdgcn_s_setprio(0);

#define GEMM256_CORE(A_PTR, BT_PTR)                                                \
    __shared__ __align__(16) char lds[131072];                                     \
    const int t = threadIdx.x;                                                     \
    const int lane = t & 63;                                                       \
    const int wid = t >> 6;                                                        \
    const int wm = wid >> 2, wn = wid & 3;                                         \
    int spr[2], scoff[2];                                                          \
    _Pragma("unroll") for (int sub = 0; sub < 2; ++sub) {                          \
        int p = sub * 8192 + t * 16;                                               \
        spr[sub] = p >> 7;                                                         \
        int spc = (p >> 4) & 7;                                                    \
        scoff[sub] = (spc ^ (spr[sub] & 7)) * 8;                                   \
    }                                                                              \
    int xa[2];                                                                     \
    _Pragma("unroll") for (int ks = 0; ks < 2; ++ks)                               \
        xa[ks] = ((ks * 4 + (lane >> 4)) ^ (lane & 7)) << 4;                       \
    const int arb = (wm * 128 + (lane & 15)) * 128;                                \
    const int brb = (wn * 64 + (lane & 15)) * 128;                                 \
    f32x4 acc[8][4] = {};                                                          \
    bf16x8 afr[4], bfr[4];                                                         \
    STAGE_H(A_PTR, 0, row0, 0, 0)                                                  \
    STAGE_H(A_PTR, 0, row0, 0, 1)                                                  \
    STAGE_H(BT_PTR, 65536, col0, 0, 0)                                             \
    STAGE_H(BT_PTR, 65536, col0, 0, 1)                                             \
    for (int kt = 0; kt < 8; ++kt) {                                               \
        const int rbuf = (kt & 1) * 32768;                                         \
        __builtin_amdgcn_s_barrier();                                              \
        if (kt < 7) {                                                              \
            STAGE_H(A_PTR, 0, row0, kt + 1, 0)                                     \
            STAGE_H(A_PTR, 0, row0, kt + 1, 1)                                     \
            STAGE_H(BT_PTR, 65536, col0, kt + 1, 0)                                \
            STAGE_H(BT_PTR, 65536, col0, kt + 1, 1)                                \
            asm volatile("s_waitcnt vmcnt(8)" ::: "memory");                       \
        } else {                                                                   \
            asm volatile("s_waitcnt vmcnt(0)" ::: "memory");                       \
        }                                                                          \
        __builtin_amdgcn_s_barrier();                                              \
        __builtin_amdgcn_sched_barrier(0);                                         \
        PHASE_A(0, 0) PHASE_B(0) PHASE_MMA(0)                                      \
        PHASE_A(1, 0) PHASE_MMA(1)                                                 \
        PHASE_A(0, 1) PHASE_B(1) PHASE_MMA(0)                                      \
        PHASE_A(1, 1) PHASE_MMA(1)                                                 \
    }

// ---------------------------------------------------------------------------
// gemm_qkv: fused qkv = w_qkv @ x.  Grid (N/256, O3/256=6, B).
// blockIdx.y < 2: q rows, softmax over d -> qT bf16 [b][n][512]
// blockIdx.y >= 2: k,v rows -> bf16 kvb [b][1024][N]
// ---------------------------------------------------------------------------
__global__ __launch_bounds__(512, 2) void gemm_qkv(const unsigned short* __restrict__ Aw,
                                                   const unsigned short* __restrict__ BTall,
                                                   unsigned short* __restrict__ qT,
                                                   unsigned short* __restrict__ kvall) {
    const int b = blockIdx.z;
    const unsigned short* A = Aw;
    const unsigned short* BT = BTall + (size_t)b * N * KDIM;
    const int row0 = blockIdx.y * 256;
    const int col0 = blockIdx.x * 256;
    GEMM256_CORE(A, BT)

    const int g = lane >> 4;
    if (blockIdx.y < 2) {
#pragma unroll
        for (int g2 = 0; g2 < 2; ++g2) {
            const int h = blockIdx.y * 4 + wm * 2 + g2;
#pragma unroll
            for (int nf = 0; nf < 4; ++nf) {
                float mx = -1e30f;
#pragma unroll
                for (int j = 0; j < 4; ++j)
#pragma unroll
                    for (int r = 0; r < 4; ++r) mx = fmaxf(mx, acc[g2 * 4 + j][nf][r]);
                mx = fmaxf(mx, __shfl_xor(mx, 16));
                mx = fmaxf(mx, __shfl_xor(mx, 32));
                float e[16];
                float s = 0.f;
#pragma unroll
                for (int j = 0; j < 4; ++j)
#pragma unroll
                    for (int r = 0; r < 4; ++r) {
                        e[j * 4 + r] = __expf(acc[g2 * 4 + j][nf][r] - mx);
                        s += e[j * 4 + r];
                    }
                s += __shfl_xor(s, 16);
                s += __shfl_xor(s, 32);
                float rs = SCALE / s;
                int n = col0 + wn * 64 + nf * 16 + (lane & 15);
                unsigned short* dst = qT + ((size_t)b * N + n) * KDIM + h * 64 + g * 4;
#pragma unroll
                for (int j = 0; j < 4; ++j) {
                    __align__(8) unsigned short o4[4] = {
                        f2bf(e[j * 4 + 0] * rs), f2bf(e[j * 4 + 1] * rs),
                        f2bf(e[j * 4 + 2] * rs), f2bf(e[j * 4 + 3] * rs)};
                    *(uint2*)(dst + j * 16) = *(const uint2*)o4;
                }
            }
        }
    } else {
        unsigned short* C = kvall + (size_t)b * 1024 * N;
        const int rbase = row0 - 512 + wm * 128;
#pragma unroll
        for (int mf = 0; mf < 8; ++mf) {
            int row_b = rbase + mf * 16 + g * 4;
#pragma unroll
            for (int nf = 0; nf < 4; ++nf) {
                int col = col0 + wn * 64 + nf * 16 + (lane & 15);
#pragma unroll
                for (int r = 0; r < 4; ++r)
                    C[(size_t)(row_b + r) * N + col] = f2bf(acc[mf][nf][r]);
            }
        }
    }
}

// ---------------------------------------------------------------------------
// context_mfma3: per (b,h,chunk): ctx[d][e] += sum_n exp(k[d,n]) * v[e,n]
// plus ksum[d] += sum_n exp(k[d,n]) via MFMA against a ones vector.
// ---------------------------------------------------------------------------
__global__ __launch_bounds__(256) void context_mfma3(const unsigned short* __restrict__ kvb,
                                                     float* __restrict__ ctx,
                                                     float* __restrict__ ksum) {
    const int ch = blockIdx.x, h = blockIdx.y, b = blockIdx.z;
    const int K0 = ch * 512;
    const unsigned short* kbase = kvb + ((size_t)b * 1024 + h * DH) * (size_t)N + K0;
    const unsigned short* vbase = kvb + ((size_t)b * 1024 + 512 + h * DH) * (size_t)N + K0;

    __shared__ __align__(16) unsigned short Ks[64 * 64];
    __shared__ __align__(16) unsigned short Vs[64 * 64];

    const int t = threadIdx.x;
    const int lane = t & 63;
    const int wv = t >> 6;

    const int kr = t >> 2;
    const int kc = (t & 3) * 16;
    const int kchunk0 = kc >> 3;
    const int kdst0 = kr * 128 + (((kchunk0 + 0) ^ (kr & 7)) << 4);
    const int kdst1 = kr * 128 + (((kchunk0 + 1) ^ (kr & 7)) << 4);

    int vrow[2], vcoff[2];
#pragma unroll
    for (int i = 0; i < 2; ++i) {
        int p = i * 4096 + t * 16;
        int pr = p >> 7;
        int pc = (p >> 4) & 7;
        vrow[i] = pr;
        vcoff[i] = (pc ^ (pr & 7)) * 8;
    }

    const int ar = wv * 16 + (lane & 15);
    int aoff[2], boff[4][2];
#pragma unroll
    for (int s = 0; s < 2; ++s) {
        int chunk = s * 4 + (lane >> 4);
        aoff[s] = ar * 128 + ((chunk ^ (ar & 7)) << 4);
#pragma unroll
        for (int nf = 0; nf < 4; ++nf) {
            int br = nf * 16 + (lane & 15);
            boff[nf][s] = br * 128 + ((chunk ^ (br & 7)) << 4);
        }
    }

    bf16x8 ones;
#pragma unroll
    for (int j = 0; j < 8; ++j) ones[j] = (short)0x3F80;

    f32x4 acc[4] = {};
    f32x4 accs = {};

    for (int k0 = 0; k0 < 512; k0 += 64) {
#pragma unroll
        for (int i = 0; i < 2; ++i)
            gload_lds16(vbase + (size_t)vrow[i] * N + k0 + vcoff[i],
                        (char*)Vs + i * 4096 + t * 16);
        __align__(16) unsigned short raw[16];
        *(uint4*)raw = *(const uint4*)(kbase + (size_t)kr * N + k0 + kc);
        *(uint4*)(raw + 8) = *(const uint4*)(kbase + (size_t)kr * N + k0 + kc + 8);
        __align__(16) unsigned short o[16];
#pragma unroll
        for (int j = 0; j < 16; ++j) o[j] = f2bf(__expf(bf2f(raw[j])));
        *(uint4*)((char*)Ks + kdst0) = *(const uint4*)o;
        *(uint4*)((char*)Ks + kdst1) = *(const uint4*)(o + 8);
        __syncthreads();

        bf16x8 av[2], bv[4][2];
#pragma unroll
        for (int s = 0; s < 2; ++s) {
            av[s] = *(const bf16x8*)((const char*)Ks + aoff[s]);
#pragma unroll
            for (int nf = 0; nf < 4; ++nf)
                bv[nf][s] = *(const bf16x8*)((const char*)Vs + boff[nf][s]);
        }
#pragma unroll
        for (int s = 0; s < 2; ++s) {
#pragma unroll
            for (int nf = 0; nf < 4; ++nf)
                acc[nf] = __builtin_amdgcn_mfma_f32_16x16x32_bf16(av[s], bv[nf][s], acc[nf], 0, 0, 0);
            accs = __builtin_amdgcn_mfma_f32_16x16x32_bf16(av[s], ones, accs, 0, 0, 0);
        }
        __syncthreads();
    }

    float* cbase = ctx + ((size_t)(b * HEADS + h)) * DH * DH;
    const int drow = wv * 16 + (lane >> 4) * 4;
#pragma unroll
    for (int nf = 0; nf < 4; ++nf) {
        int e = nf * 16 + (lane & 15);
#pragma unroll
        for (int rr = 0; rr < 4; ++rr)
            atomicAdd(&cbase[(drow + rr) * DH + e], acc[nf][rr]);
    }
    if ((lane & 15) == 0) {
#pragma unroll
        for (int rr = 0; rr < 4; ++rr)
            atomicAdd(&ksum[b * 512 + h * DH + drow + rr], accs[rr]);
    }
}

// ---------------------------------------------------------------------------
// fold_wout3: per (b,h): W2[o][d] = sum_e w_out[o][h*64+e] * ctx[b,h,d,e]/ksum[d]
// ---------------------------------------------------------------------------
__global__ __launch_bounds__(256) void fold_wout3(const float* __restrict__ w_out,
                                                  const float* __restrict__ ctx,
                                                  const float* __restrict__ ksum,
                                                  unsigned short* __restrict__ w2) {
    const int ot = blockIdx.x, h = blockIdx.y, b = blockIdx.z;
    __shared__ __align__(16) unsigned short As[128 * 64];
    __shared__ __align__(16) unsigned short Bs[64 * 64];
    const int t = threadIdx.x;
    const int lane = t & 63;
    const int wv = t >> 6;

#pragma unroll
    for (int i = 0; i < 8; ++i) {
        int lin = t + i * 256;
        int r = lin >> 4;
        int c4 = (lin & 15) * 4;
        float4 v = *(const float4*)(w_out + (size_t)(ot * 128 + r) * HID + h * 64 + c4);
        __align__(8) unsigned short o4[4] = {f2bf(v.x), f2bf(v.y), f2bf(v.z), f2bf(v.w)};
        int chunk = c4 >> 3;
        int off = (c4 & 7) * 2;
        *(uint2*)((char*)As + r * 128 + ((chunk ^ (r & 7)) << 4) + off) = *(const uint2*)o4;
    }
    const float* cb = ctx + ((size_t)(b * HEADS + h)) * DH * DH;
    const float* ks = ksum + b * 512 + h * 64;
#pragma unroll
    for (int i = 0; i < 4; ++i) {
        int lin = t + i * 256;
        int r = lin >> 4;
        int c4 = (lin & 15) * 4;
        float inv = 1.0f / ks[r];
        float4 v = *(const float4*)(cb + (size_t)r * DH + c4);
        __align__(8) unsigned short o4[4] = {f2bf(v.x * inv), f2bf(v.y * inv),
                                             f2bf(v.z * inv), f2bf(v.w * inv)};
        int chunk = c4 >> 3;
        int off = (c4 & 7) * 2;
        *(uint2*)((char*)Bs + r * 128 + ((chunk ^ (r & 7)) << 4) + off) = *(const uint2*)o4;
    }
    __syncthreads();

    f32x4 acc[2][4] = {};
#pragma unroll
    for (int s = 0; s < 2; ++s) {
        int chunk = s * 4 + (lane >> 4);
        bf16x8 bf[4];
#pragma unroll
        for (int nf = 0; nf < 4; ++nf) {
            int brow = nf * 16 + (lane & 15);
            bf[nf] = *(const bf16x8*)((const char*)Bs + brow * 128 + ((chunk ^ (brow & 7)) << 4));
        }
#pragma unroll
        for (int mm = 0; mm < 2; ++mm) {
            int arow = (wv * 2 + mm) * 16 + (lane & 15);
            bf16x8 a = *(const bf16x8*)((const char*)As + arow * 128 + ((chunk ^ (arow & 7)) << 4));
#pragma unroll
            for (int nf = 0; nf < 4; ++nf)
                acc[mm][nf] = __builtin_amdgcn_mfma_f32_16x16x32_bf16(a, bf[nf], acc[mm][nf], 0, 0, 0);
        }
    }

#pragma unroll
    for (int mm = 0; mm < 2; ++mm) {
        int o_base = ot * 128 + (wv * 2 + mm) * 16 + (lane >> 4) * 4;
#pragma unroll
        for (int nf = 0; nf < 4; ++nf) {
            int d = nf * 16 + (lane & 15);
#pragma unroll
            for (int rr = 0; rr < 4; ++rr)
                w2[((size_t)(b * D) + o_base + rr) * D + h * 64 + d] = f2bf(acc[mm][nf][rr]);
        }
    }
}

// ---------------------------------------------------------------------------
// gemm_y_fused: full-column y GEMM + in-block RMSNorm, BK=32.
// Grid (N/64, 1, B), 512 threads = 8 waves, tile M=512 x N=64.
// LDS 72KB (A dbuf 2x32KB at 0, B dbuf 2x4KB at 65536) -> 2 blocks/CU
// naturally (VGPR ~112 -> 4 waves/SIMD; no min-waves cap, R16 lesson).
// A staged by all (4 gloads/thread); B by waves 0-3 only (wave-uniform
// branch) -> wave-uniform vmcnt(5)/vmcnt(4). 2-barrier schedule as the
// 256-core; indexing validated in R16 (passed absmax).
// Epilogue: bias + per-column sum(y^2) cross-wave LDS reduce + final scale.
// ---------------------------------------------------------------------------
#define YSTAGE32(KT)                                                               \
    _Pragma("unroll") for (int sub = 0; sub < 4; ++sub)                            \
        gload_lds16(A + (size_t)(sub * 128 + (t >> 2)) * KDIM + (KT) * 32 + sco,   \
                    lds + ((KT) & 1) * 32768 + sub * 8192 + t * 16);               \
    if (t < 256)                                                                   \
        gload_lds16(BT + (size_t)(col0 + (t >> 2)) * KDIM + (KT) * 32 + sco,       \
                    lds + 65536 + ((KT) & 1) * 4096 + t * 16);

__global__ __launch_bounds__(512) void gemm_y_fused(const unsigned short* __restrict__ w2all,
                                                    const unsigned short* __restrict__ qTall,
                                                    const float* __restrict__ bias,
                                                    const float* __restrict__ g,
                                                    float* __restrict__ outall) {
    const int b = blockIdx.z;
    const unsigned short* A = w2all + (size_t)b * D * D;
    const unsigned short* BT = qTall + (size_t)b * N * KDIM;
    float* out = outall + (size_t)b * D * N;
    const int col0 = blockIdx.x * 64;

    __shared__ __align__(16) char lds[73728];
    const int t = threadIdx.x;
    const int lane = t & 63;
    const int wid = t >> 6;

    const int sco = ((t & 3) ^ ((t >> 3) & 3)) * 8;
    const int xa = (((lane >> 4) ^ (((lane & 15) >> 1) & 3))) << 4;
    const int arb = (wid * 64 + (lane & 15)) * 64;
    const int brb = (lane & 15) * 64;

    f32x4 acc[4][4] = {};
    bf16x8 afr[4], bfr[4];

    YSTAGE32(0)
    for (int kt = 0; kt < 16; ++kt) {
        const int abuf = (kt & 1) * 32768;
        const int bbuf = 65536 + (kt & 1) * 4096;
        __builtin_amdgcn_s_barrier();
        if (kt < 15) {
            YSTAGE32(kt + 1)
            if (wid < 4) {
                asm volatile("s_waitcnt vmcnt(5)" ::: "memory");
            } else {
                asm volatile("s_waitcnt vmcnt(4)" ::: "memory");
            }
        } else {
            asm volatile("s_waitcnt vmcnt(0)" ::: "memory");
        }
        __builtin_amdgcn_s_barrier();
        __builtin_amdgcn_sched_barrier(0);
#pragma unroll
        for (int mf = 0; mf < 4; ++mf)
            afr[mf] = *(const bf16x8*)(lds + abuf + arb + mf * 1024 + xa);
#pragma unroll
        for (int nf = 0; nf < 4; ++nf)
            bfr[nf] = *(const bf16x8*)(lds + bbuf + brb + nf * 1024 + xa);
        asm volatile("s_waitcnt lgkmcnt(0)" ::: "memory");
        __builtin_amdgcn_sched_barrier(0);
        __builtin_amdgcn_s_setprio(1);
#pragma unroll
        for (int mf = 0; mf < 4; ++mf)
#pragma unroll
            for (int nf = 0; nf < 4; ++nf)
                acc[mf][nf] = __builtin_amdgcn_mfma_f32_16x16x32_bf16(
                    afr[mf], bfr[nf], acc[mf][nf], 0, 0, 0);
        __builtin_amdgcn_s_setprio(0);
    }

    // epilogue: bias add + per-column sum(y^2)
    float csum[4] = {0.f, 0.f, 0.f, 0.f};
#pragma unroll
    for (int mf = 0; mf < 4; ++mf) {
        int row = wid * 64 + mf * 16 + (lane >> 4) * 4;
#pragma unroll
        for (int r = 0; r < 4; ++r) {
            float bv = bias[row + r];
#pragma unroll
            for (int nf = 0; nf < 4; ++nf) {
                acc[mf][nf][r] += bv;
                csum[nf] += acc[mf][nf][r] * acc[mf][nf][r];
            }
        }
    }
#pragma unroll
    for (int nf = 0; nf < 4; ++nf) {
        csum[nf] += __shfl_xor(csum[nf], 16);
        csum[nf] += __shfl_xor(csum[nf], 32);
    }
    __syncthreads();
    float* scr = (float*)lds;
    if (lane < 16) {
#pragma unroll
        for (int nf = 0; nf < 4; ++nf) scr[wid * 64 + nf * 16 + lane] = csum[nf];
    }
    __syncthreads();
    float rinv[4];
#pragma unroll
    for (int nf = 0; nf < 4; ++nf) {
        int c = nf * 16 + (lane & 15);
        float s = 0.f;
#pragma unroll
        for (int w = 0; w < 8; ++w) s += scr[w * 64 + c];
        rinv[nf] = SQRT_D / fmaxf(sqrtf(s), 1e-12f);
    }
#pragma unroll
    for (int mf = 0; mf < 4; ++mf) {
        int row = wid * 64 + mf * 16 + (lane >> 4) * 4;
#pragma unroll
        for (int r = 0; r < 4; ++r) {
            float gv = g[row + r];
#pragma unroll
            for (int nf = 0; nf < 4; ++nf) {
                int col = col0 + nf * 16 + (lane & 15);
                out[(size_t)(row + r) * N + col] = acc[mf][nf][r] * rinv[nf] * gv;
            }
        }
    }
}

extern "C" void kernel_launch(void* const* d_in, const int* in_sizes, int n_in,
                              void* d_out, int out_size, void* d_ws, size_t ws_size,
                              hipStream_t stream) {
    const float* x = (const float*)d_in[0];
    const float* w_qkv = (const float*)d_in[1];
    const float* w_out = (const float*)d_in[2];
    const float* b_out = (const float*)d_in[3];
    const float* g = (const float*)d_in[4];
    float* out = (float*)d_out;

    // workspace layout
    unsigned short* kvb = (unsigned short*)d_ws;                 // 64 MB
    float* ctx = (float*)(kvb + (size_t)B * 1024 * N);           // 1 MB
    float* ksum = ctx + (size_t)B * HEADS * DH * DH;             // 16 KB
    unsigned short* w2 = (unsigned short*)(ksum + B * 512);      // 4 MB
    unsigned short* wqb = w2 + (size_t)B * D * D;                // 1.5 MB
    unsigned short* xT = wqb + (size_t)O3 * KDIM;                // 32 MB
    unsigned short* qT = xT + (size_t)B * N * KDIM;              // 32 MB

    // zero ctx + ksum (contiguous)
    hipMemsetAsync(ctx, 0, ((size_t)B * HEADS * DH * DH + B * 512) * sizeof(float), stream);

    prep<<<dim3(96, 8, B + 1), 256, 0, stream>>>(x, xT, w_qkv, wqb);

    gemm_qkv<<<dim3(N / 256, O3 / 256, B), 512, 0, stream>>>(wqb, xT, qT, kvb);

    context_mfma3<<<dim3(8, HEADS, B), 256, 0, stream>>>(kvb, ctx, ksum);
    fold_wout3<<<dim3(4, HEADS, B), 256, 0, stream>>>(w_out, ctx, ksum, w2);

    gemm_y_fused<<<dim3(N / 64, 1, B), 512, 0, stream>>>(w2, qT, b_out, g, out);
}

// Round 19
// 145.782 us; speedup vs baseline: 1.0250x; 1.0250x over previous
//
#include <hip/hip_runtime.h>
#include <math.h>

#define B 8
#define D 512
#define N 4096
#define HEADS 8
#define DH 64
#define HID 512
#define O3 1536
#define KDIM 512
#define SCALE 0.125f
#define SQRT_D 22.62741699796952f

typedef __attribute__((ext_vector_type(4))) float f32x4;
typedef __attribute__((ext_vector_type(8))) short bf16x8;

static __device__ __forceinline__ unsigned short f2bf(float f) {
    unsigned int u = __float_as_uint(f);
    unsigned int r = (u + 0x7fffu + ((u >> 16) & 1u)) >> 16;
    return (unsigned short)r;
}

static __device__ __forceinline__ float bf2f(unsigned short u) {
    return __uint_as_float((unsigned int)u << 16);
}

static __device__ __forceinline__ void gload_lds16(const void* g, void* l) {
    __builtin_amdgcn_global_load_lds(
        (const __attribute__((address_space(1))) unsigned int*)g,
        (__attribute__((address_space(3))) unsigned int*)l, 16, 0, 0);
}

// ---------------------------------------------------------------------------
// prep: fused cvt_w + transpose_x.
// grid (96, 8, 9): z<8 & x<64 -> transpose x[b]; z==8 -> cvt w_qkv.
// ---------------------------------------------------------------------------
__global__ __launch_bounds__(256) void prep(const float* __restrict__ x,
                                            unsigned short* __restrict__ xT,
                                            const float* __restrict__ w,
                                            unsigned short* __restrict__ wb) {
    if (blockIdx.z == B) {
        int i = ((blockIdx.y * 96 + blockIdx.x) * 256 + threadIdx.x) * 4;
        float4 v = *(const float4*)(w + i);
        __align__(8) unsigned short o[4] = {f2bf(v.x), f2bf(v.y), f2bf(v.z), f2bf(v.w)};
        *(uint2*)(wb + i) = *(const uint2*)o;
        return;
    }
    if (blockIdx.x >= 64) return;
    __shared__ float tile[64][65];
    const int n0 = blockIdx.x * 64, d0 = blockIdx.y * 64, b = blockIdx.z;
    const float* xb = x + (size_t)b * D * N;
    unsigned short* xTb = xT + (size_t)b * N * KDIM;
    const int t = threadIdx.x;
    const int r = t >> 4, c4 = (t & 15) * 4;
#pragma unroll
    for (int i = 0; i < 4; ++i) {
        int row = r + i * 16;
        float4 v = *(const float4*)(xb + (size_t)(d0 + row) * N + n0 + c4);
        tile[row][c4 + 0] = v.x;
        tile[row][c4 + 1] = v.y;
        tile[row][c4 + 2] = v.z;
        tile[row][c4 + 3] = v.w;
    }
    __syncthreads();
#pragma unroll
    for (int pass = 0; pass < 2; ++pass) {
        int orow = (t >> 3) + pass * 32;
        int oc = (t & 7) * 8;
        __align__(16) unsigned short o[8];
#pragma unroll
        for (int e = 0; e < 8; ++e) o[e] = f2bf(tile[oc + e][orow]);
        *(uint4*)(xTb + (size_t)(n0 + orow) * KDIM + d0 + oc) = *(const uint4*)o;
    }
}

// ---------------------------------------------------------------------------
// 256x256 8-wave GEMM core (best race-free variant, R13/R15/R17):
// full-tile prefetch, 2 barriers/K-tile, counted vmcnt(8), chunk-XOR
// swizzle on both staging source and ds_read. No min-waves launch_bounds:
// acc[8][4]=128 VGPRs makes 2 blocks/CU impossible (R16: capping spills).
// ---------------------------------------------------------------------------
#define STAGE_H(PTR, REGION, TILE0, KT, H)                                         \
    _Pragma("unroll") for (int sub = 0; sub < 2; ++sub)                            \
        gload_lds16(PTR + (size_t)((TILE0) + (H) * 128 + spr[sub]) * KDIM          \
                        + (KT) * 64 + scoff[sub],                                  \
                    lds + (REGION) + ((KT) & 1) * 32768 + (H) * 16384              \
                        + sub * 8192 + t * 16);

#define PHASE_A(MG, KS)                                                            \
    _Pragma("unroll") for (int j = 0; j < 4; ++j)                                  \
        afr[j] = *(const bf16x8*)(lds + rbuf + arb + ((MG) * 4 + j) * 2048 + xa[KS]);

#define PHASE_B(KS)                                                               \
    _Pragma("unroll") for (int nf = 0; nf < 4; ++nf)                               \
        bfr[nf] = *(const bf16x8*)(lds + 65536 + rbuf + brb + nf * 2048 + xa[KS]);

#define PHASE_MMA(MG)                                                              \
    asm volatile("s_waitcnt lgkmcnt(0)" ::: "memory");                             \
    __builtin_amdgcn_sched_barrier(0);                                             \
    __builtin_amdgcn_s_setprio(1);                                                 \
    _Pragma("unroll") for (int j = 0; j < 4; ++j)                                  \
        _Pragma("unroll") for (int nf = 0; nf < 4; ++nf)                           \
            acc[(MG) * 4 + j][nf] = __builtin_amdgcn_mfma_f32_16x16x32_bf16(       \
                afr[j], bfr[nf], acc[(MG) * 4 + j][nf], 0, 0, 0);                  \
    __builtin_amdgcn_s_setprio(0);

#define GEMM256_CORE(A_PTR, BT_PTR)                                                \
    __shared__ __align__(16) char lds[131072];                                     \
    const int t = threadIdx.x;                                                     \
    const int lane = t & 63;                                                       \
    const int wid = t >> 6;                                                        \
    const int wm = wid >> 2, wn = wid & 3;                                         \
    int spr[2], scoff[2];                                                          \
    _Pragma("unroll") for (int sub = 0; sub < 2; ++sub) {                          \
        int p = sub * 8192 + t * 16;                                               \
        spr[sub] = p >> 7;                                                         \
        int spc = (p >> 4) & 7;                                                    \
        scoff[sub] = (spc ^ (spr[sub] & 7)) * 8;                                   \
    }                                                                              \
    int xa[2];                                                                     \
    _Pragma("unroll") for (int ks = 0; ks < 2; ++ks)                               \
        xa[ks] = ((ks * 4 + (lane >> 4)) ^ (lane & 7)) << 4;                       \
    const int arb = (wm * 128 + (lane & 15)) * 128;                                \
    const int brb = (wn * 64 + (lane & 15)) * 128;                                 \
    f32x4 acc[8][4] = {};                                                          \
    bf16x8 afr[4], bfr[4];                                                         \
    STAGE_H(A_PTR, 0, row0, 0, 0)                                                  \
    STAGE_H(A_PTR, 0, row0, 0, 1)                                                  \
    STAGE_H(BT_PTR, 65536, col0, 0, 0)                                             \
    STAGE_H(BT_PTR, 65536, col0, 0, 1)                                             \
    for (int kt = 0; kt < 8; ++kt) {                                               \
        const int rbuf = (kt & 1) * 32768;                                         \
        __builtin_amdgcn_s_barrier();                                              \
        if (kt < 7) {                                                              \
            STAGE_H(A_PTR, 0, row0, kt + 1, 0)                                     \
            STAGE_H(A_PTR, 0, row0, kt + 1, 1)                                     \
            STAGE_H(BT_PTR, 65536, col0, kt + 1, 0)                                \
            STAGE_H(BT_PTR, 65536, col0, kt + 1, 1)                                \
            asm volatile("s_waitcnt vmcnt(8)" ::: "memory");                       \
        } else {                                                                   \
            asm volatile("s_waitcnt vmcnt(0)" ::: "memory");                       \
        }                                                                          \
        __builtin_amdgcn_s_barrier();                                              \
        __builtin_amdgcn_sched_barrier(0);                                         \
        PHASE_A(0, 0) PHASE_B(0) PHASE_MMA(0)                                      \
        PHASE_A(1, 0) PHASE_MMA(1)                                                 \
        PHASE_A(0, 1) PHASE_B(1) PHASE_MMA(0)                                      \
        PHASE_A(1, 1) PHASE_MMA(1)                                                 \
    }

// ---------------------------------------------------------------------------
// gemm_qkv: fused qkv = w_qkv @ x.  Grid (N/256, O3/256=6, B).
// blockIdx.y < 2: q rows, softmax over d -> qT bf16 [b][n][512]
// blockIdx.y >= 2: k,v rows -> bf16 kvb [b][1024][N]
// ---------------------------------------------------------------------------
__global__ __launch_bounds__(512, 2) void gemm_qkv(const unsigned short* __restrict__ Aw,
                                                   const unsigned short* __restrict__ BTall,
                                                   unsigned short* __restrict__ qT,
                                                   unsigned short* __restrict__ kvall) {
    const int b = blockIdx.z;
    const unsigned short* A = Aw;
    const unsigned short* BT = BTall + (size_t)b * N * KDIM;
    const int row0 = blockIdx.y * 256;
    const int col0 = blockIdx.x * 256;
    GEMM256_CORE(A, BT)

    const int g = lane >> 4;
    if (blockIdx.y < 2) {
#pragma unroll
        for (int g2 = 0; g2 < 2; ++g2) {
            const int h = blockIdx.y * 4 + wm * 2 + g2;
#pragma unroll
            for (int nf = 0; nf < 4; ++nf) {
                float mx = -1e30f;
#pragma unroll
                for (int j = 0; j < 4; ++j)
#pragma unroll
                    for (int r = 0; r < 4; ++r) mx = fmaxf(mx, acc[g2 * 4 + j][nf][r]);
                mx = fmaxf(mx, __shfl_xor(mx, 16));
                mx = fmaxf(mx, __shfl_xor(mx, 32));
                float e[16];
                float s = 0.f;
#pragma unroll
                for (int j = 0; j < 4; ++j)
#pragma unroll
                    for (int r = 0; r < 4; ++r) {
                        e[j * 4 + r] = __expf(acc[g2 * 4 + j][nf][r] - mx);
                        s += e[j * 4 + r];
                    }
                s += __shfl_xor(s, 16);
                s += __shfl_xor(s, 32);
                float rs = SCALE / s;
                int n = col0 + wn * 64 + nf * 16 + (lane & 15);
                unsigned short* dst = qT + ((size_t)b * N + n) * KDIM + h * 64 + g * 4;
#pragma unroll
                for (int j = 0; j < 4; ++j) {
                    __align__(8) unsigned short o4[4] = {
                        f2bf(e[j * 4 + 0] * rs), f2bf(e[j * 4 + 1] * rs),
                        f2bf(e[j * 4 + 2] * rs), f2bf(e[j * 4 + 3] * rs)};
                    *(uint2*)(dst + j * 16) = *(const uint2*)o4;
                }
            }
        }
    } else {
        unsigned short* C = kvall + (size_t)b * 1024 * N;
        const int rbase = row0 - 512 + wm * 128;
#pragma unroll
        for (int mf = 0; mf < 8; ++mf) {
            int row_b = rbase + mf * 16 + g * 4;
#pragma unroll
            for (int nf = 0; nf < 4; ++nf) {
                int col = col0 + wn * 64 + nf * 16 + (lane & 15);
#pragma unroll
                for (int r = 0; r < 4; ++r)
                    C[(size_t)(row_b + r) * N + col] = f2bf(acc[mf][nf][r]);
            }
        }
    }
}

// ---------------------------------------------------------------------------
// context_mfma3: per (b,h,chunk): ctx[d][e] += sum_n exp(k[d,n]) * v[e,n]
// plus ksum[d] += sum_n exp(k[d,n]) via MFMA against a ones vector.
// ---------------------------------------------------------------------------
__global__ __launch_bounds__(256) void context_mfma3(const unsigned short* __restrict__ kvb,
                                                     float* __restrict__ ctx,
                                                     float* __restrict__ ksum) {
    const int ch = blockIdx.x, h = blockIdx.y, b = blockIdx.z;
    const int K0 = ch * 512;
    const unsigned short* kbase = kvb + ((size_t)b * 1024 + h * DH) * (size_t)N + K0;
    const unsigned short* vbase = kvb + ((size_t)b * 1024 + 512 + h * DH) * (size_t)N + K0;

    __shared__ __align__(16) unsigned short Ks[64 * 64];
    __shared__ __align__(16) unsigned short Vs[64 * 64];

    const int t = threadIdx.x;
    const int lane = t & 63;
    const int wv = t >> 6;

    const int kr = t >> 2;
    const int kc = (t & 3) * 16;
    const int kchunk0 = kc >> 3;
    const int kdst0 = kr * 128 + (((kchunk0 + 0) ^ (kr & 7)) << 4);
    const int kdst1 = kr * 128 + (((kchunk0 + 1) ^ (kr & 7)) << 4);

    int vrow[2], vcoff[2];
#pragma unroll
    for (int i = 0; i < 2; ++i) {
        int p = i * 4096 + t * 16;
        int pr = p >> 7;
        int pc = (p >> 4) & 7;
        vrow[i] = pr;
        vcoff[i] = (pc ^ (pr & 7)) * 8;
    }

    const int ar = wv * 16 + (lane & 15);
    int aoff[2], boff[4][2];
#pragma unroll
    for (int s = 0; s < 2; ++s) {
        int chunk = s * 4 + (lane >> 4);
        aoff[s] = ar * 128 + ((chunk ^ (ar & 7)) << 4);
#pragma unroll
        for (int nf = 0; nf < 4; ++nf) {
            int br = nf * 16 + (lane & 15);
            boff[nf][s] = br * 128 + ((chunk ^ (br & 7)) << 4);
        }
    }

    bf16x8 ones;
#pragma unroll
    for (int j = 0; j < 8; ++j) ones[j] = (short)0x3F80;

    f32x4 acc[4] = {};
    f32x4 accs = {};

    for (int k0 = 0; k0 < 512; k0 += 64) {
#pragma unroll
        for (int i = 0; i < 2; ++i)
            gload_lds16(vbase + (size_t)vrow[i] * N + k0 + vcoff[i],
                        (char*)Vs + i * 4096 + t * 16);
        __align__(16) unsigned short raw[16];
        *(uint4*)raw = *(const uint4*)(kbase + (size_t)kr * N + k0 + kc);
        *(uint4*)(raw + 8) = *(const uint4*)(kbase + (size_t)kr * N + k0 + kc + 8);
        __align__(16) unsigned short o[16];
#pragma unroll
        for (int j = 0; j < 16; ++j) o[j] = f2bf(__expf(bf2f(raw[j])));
        *(uint4*)((char*)Ks + kdst0) = *(const uint4*)o;
        *(uint4*)((char*)Ks + kdst1) = *(const uint4*)(o + 8);
        __syncthreads();

        bf16x8 av[2], bv[4][2];
#pragma unroll
        for (int s = 0; s < 2; ++s) {
            av[s] = *(const bf16x8*)((const char*)Ks + aoff[s]);
#pragma unroll
            for (int nf = 0; nf < 4; ++nf)
                bv[nf][s] = *(const bf16x8*)((const char*)Vs + boff[nf][s]);
        }
#pragma unroll
        for (int s = 0; s < 2; ++s) {
#pragma unroll
            for (int nf = 0; nf < 4; ++nf)
                acc[nf] = __builtin_amdgcn_mfma_f32_16x16x32_bf16(av[s], bv[nf][s], acc[nf], 0, 0, 0);
            accs = __builtin_amdgcn_mfma_f32_16x16x32_bf16(av[s], ones, accs, 0, 0, 0);
        }
        __syncthreads();
    }

    float* cbase = ctx + ((size_t)(b * HEADS + h)) * DH * DH;
    const int drow = wv * 16 + (lane >> 4) * 4;
#pragma unroll
    for (int nf = 0; nf < 4; ++nf) {
        int e = nf * 16 + (lane & 15);
#pragma unroll
        for (int rr = 0; rr < 4; ++rr)
            atomicAdd(&cbase[(drow + rr) * DH + e], acc[nf][rr]);
    }
    if ((lane & 15) == 0) {
#pragma unroll
        for (int rr = 0; rr < 4; ++rr)
            atomicAdd(&ksum[b * 512 + h * DH + drow + rr], accs[rr]);
    }
}

// ---------------------------------------------------------------------------
// fold_wout3: per (b,h): W2[o][d] = sum_e w_out[o][h*64+e] * ctx[b,h,d,e]/ksum[d]
// ---------------------------------------------------------------------------
__global__ __launch_bounds__(256) void fold_wout3(const float* __restrict__ w_out,
                                                  const float* __restrict__ ctx,
                                                  const float* __restrict__ ksum,
                                                  unsigned short* __restrict__ w2) {
    const int ot = blockIdx.x, h = blockIdx.y, b = blockIdx.z;
    __shared__ __align__(16) unsigned short As[128 * 64];
    __shared__ __align__(16) unsigned short Bs[64 * 64];
    const int t = threadIdx.x;
    const int lane = t & 63;
    const int wv = t >> 6;

#pragma unroll
    for (int i = 0; i < 8; ++i) {
        int lin = t + i * 256;
        int r = lin >> 4;
        int c4 = (lin & 15) * 4;
        float4 v = *(const float4*)(w_out + (size_t)(ot * 128 + r) * HID + h * 64 + c4);
        __align__(8) unsigned short o4[4] = {f2bf(v.x), f2bf(v.y), f2bf(v.z), f2bf(v.w)};
        int chunk = c4 >> 3;
        int off = (c4 & 7) * 2;
        *(uint2*)((char*)As + r * 128 + ((chunk ^ (r & 7)) << 4) + off) = *(const uint2*)o4;
    }
    const float* cb = ctx + ((size_t)(b * HEADS + h)) * DH * DH;
    const float* ks = ksum + b * 512 + h * 64;
#pragma unroll
    for (int i = 0; i < 4; ++i) {
        int lin = t + i * 256;
        int r = lin >> 4;
        int c4 = (lin & 15) * 4;
        float inv = 1.0f / ks[r];
        float4 v = *(const float4*)(cb + (size_t)r * DH + c4);
        __align__(8) unsigned short o4[4] = {f2bf(v.x * inv), f2bf(v.y * inv),
                                             f2bf(v.z * inv), f2bf(v.w * inv)};
        int chunk = c4 >> 3;
        int off = (c4 & 7) * 2;
        *(uint2*)((char*)Bs + r * 128 + ((chunk ^ (r & 7)) << 4) + off) = *(const uint2*)o4;
    }
    __syncthreads();

    f32x4 acc[2][4] = {};
#pragma unroll
    for (int s = 0; s < 2; ++s) {
        int chunk = s * 4 + (lane >> 4);
        bf16x8 bf[4];
#pragma unroll
        for (int nf = 0; nf < 4; ++nf) {
            int brow = nf * 16 + (lane & 15);
            bf[nf] = *(const bf16x8*)((const char*)Bs + brow * 128 + ((chunk ^ (brow & 7)) << 4));
        }
#pragma unroll
        for (int mm = 0; mm < 2; ++mm) {
            int arow = (wv * 2 + mm) * 16 + (lane & 15);
            bf16x8 a = *(const bf16x8*)((const char*)As + arow * 128 + ((chunk ^ (arow & 7)) << 4));
#pragma unroll
            for (int nf = 0; nf < 4; ++nf)
                acc[mm][nf] = __builtin_amdgcn_mfma_f32_16x16x32_bf16(a, bf[nf], acc[mm][nf], 0, 0, 0);
        }
    }

#pragma unroll
    for (int mm = 0; mm < 2; ++mm) {
        int o_base = ot * 128 + (wv * 2 + mm) * 16 + (lane >> 4) * 4;
#pragma unroll
        for (int nf = 0; nf < 4; ++nf) {
            int d = nf * 16 + (lane & 15);
#pragma unroll
            for (int rr = 0; rr < 4; ++rr)
                w2[((size_t)(b * D) + o_base + rr) * D + h * 64 + d] = f2bf(acc[mm][nf][rr]);
        }
    }
}

// ---------------------------------------------------------------------------
// gemm_y_fused: full-column y GEMM + in-block RMSNorm (R15/R17 version).
// Grid (N/64, 1, B), 512 threads = 8 waves, tile M=512 x N=64, BK=64.
// LDS 144KB: A dbuf [2][512][64] bf16 at 0 (2x64KB), B dbuf at 131072
// (2x8KB). Epilogue: bias add, per-column sum(y^2) via shfl + cross-wave
// LDS scratch, out = y * SQRT_D/max(sqrt(colsum),eps) * g[row] written once.
// ---------------------------------------------------------------------------
#define YSTAGE(KT)                                                                 \
    _Pragma("unroll") for (int sub = 0; sub < 8; ++sub)                            \
        gload_lds16(A + (size_t)(sub * 64 + srow) * KDIM + (KT) * 64 + sco,        \
                    lds + ((KT) & 1) * 65536 + sub * 8192 + t * 16);               \
    gload_lds16(BT + (size_t)(col0 + srow) * KDIM + (KT) * 64 + sco,               \
                lds + 131072 + ((KT) & 1) * 8192 + t * 16);

__global__ __launch_bounds__(512, 1) void gemm_y_fused(const unsigned short* __restrict__ w2all,
                                                       const unsigned short* __restrict__ qTall,
                                                       const float* __restrict__ bias,
                                                       const float* __restrict__ g,
                                                       float* __restrict__ outall) {
    const int b = blockIdx.z;
    const unsigned short* A = w2all + (size_t)b * D * D;
    const unsigned short* BT = qTall + (size_t)b * N * KDIM;
    float* out = outall + (size_t)b * D * N;
    const int col0 = blockIdx.x * 64;

    __shared__ __align__(16) char lds[147456];
    const int t = threadIdx.x;
    const int lane = t & 63;
    const int wid = t >> 6;

    const int srow = t >> 3;
    const int sco = ((t & 7) ^ (srow & 7)) * 8;

    int xa[2];
#pragma unroll
    for (int ks = 0; ks < 2; ++ks)
        xa[ks] = ((ks * 4 + (lane >> 4)) ^ (lane & 7)) << 4;
    const int arb = (wid * 64 + (lane & 15)) * 128;
    const int brb = (lane & 15) * 128;

    f32x4 acc[4][4] = {};
    bf16x8 afr[4], bfr[4];

    YSTAGE(0)
    for (int kt = 0; kt < 8; ++kt) {
        const int abuf = (kt & 1) * 65536;
        const int bbuf = 131072 + (kt & 1) * 8192;
        __builtin_amdgcn_s_barrier();
        if (kt < 7) {
            YSTAGE(kt + 1)
            asm volatile("s_waitcnt vmcnt(9)" ::: "memory");
        } else {
            asm volatile("s_waitcnt vmcnt(0)" ::: "memory");
        }
        __builtin_amdgcn_s_barrier();
        __builtin_amdgcn_sched_barrier(0);
#pragma unroll
        for (int ks = 0; ks < 2; ++ks) {
#pragma unroll
            for (int mf = 0; mf < 4; ++mf)
                afr[mf] = *(const bf16x8*)(lds + abuf + arb + mf * 2048 + xa[ks]);
#pragma unroll
            for (int nf = 0; nf < 4; ++nf)
                bfr[nf] = *(const bf16x8*)(lds + bbuf + brb + nf * 2048 + xa[ks]);
            asm volatile("s_waitcnt lgkmcnt(0)" ::: "memory");
            __builtin_amdgcn_sched_barrier(0);
            __builtin_amdgcn_s_setprio(1);
#pragma unroll
            for (int mf = 0; mf < 4; ++mf)
#pragma unroll
                for (int nf = 0; nf < 4; ++nf)
                    acc[mf][nf] = __builtin_amdgcn_mfma_f32_16x16x32_bf16(
                        afr[mf], bfr[nf], acc[mf][nf], 0, 0, 0);
            __builtin_amdgcn_s_setprio(0);
        }
    }

    // epilogue: bias add + per-column sum(y^2)
    float csum[4] = {0.f, 0.f, 0.f, 0.f};
#pragma unroll
    for (int mf = 0; mf < 4; ++mf) {
        int row = wid * 64 + mf * 16 + (lane >> 4) * 4;
#pragma unroll
        for (int r = 0; r < 4; ++r) {
            float bv = bias[row + r];
#pragma unroll
            for (int nf = 0; nf < 4; ++nf) {
                acc[mf][nf][r] += bv;
                csum[nf] += acc[mf][nf][r] * acc[mf][nf][r];
            }
        }
    }
#pragma unroll
    for (int nf = 0; nf < 4; ++nf) {
        csum[nf] += __shfl_xor(csum[nf], 16);
        csum[nf] += __shfl_xor(csum[nf], 32);
    }
    __syncthreads();  // all waves done with main-loop LDS
    float* scr = (float*)lds;  // [8 waves][64 cols]
    if (lane < 16) {
#pragma unroll
        for (int nf = 0; nf < 4; ++nf) scr[wid * 64 + nf * 16 + lane] = csum[nf];
    }
    __syncthreads();
    float rinv[4];
#pragma unroll
    for (int nf = 0; nf < 4; ++nf) {
        int c = nf * 16 + (lane & 15);
        float s = 0.f;
#pragma unroll
        for (int w = 0; w < 8; ++w) s += scr[w * 64 + c];
        rinv[nf] = SQRT_D / fmaxf(sqrtf(s), 1e-12f);
    }
#pragma unroll
    for (int mf = 0; mf < 4; ++mf) {
        int row = wid * 64 + mf * 16 + (lane >> 4) * 4;
#pragma unroll
        for (int r = 0; r < 4; ++r) {
            float gv = g[row + r];
#pragma unroll
            for (int nf = 0; nf < 4; ++nf) {
                int col = col0 + nf * 16 + (lane & 15);
                out[(size_t)(row + r) * N + col] = acc[mf][nf][r] * rinv[nf] * gv;
            }
        }
    }
}

extern "C" void kernel_launch(void* const* d_in, const int* in_sizes, int n_in,
                              void* d_out, int out_size, void* d_ws, size_t ws_size,
                              hipStream_t stream) {
    const float* x = (const float*)d_in[0];
    const float* w_qkv = (const float*)d_in[1];
    const float* w_out = (const float*)d_in[2];
    const float* b_out = (const float*)d_in[3];
    const float* g = (const float*)d_in[4];
    float* out = (float*)d_out;

    // workspace layout
    unsigned short* kvb = (unsigned short*)d_ws;                 // 64 MB
    float* ctx = (float*)(kvb + (size_t)B * 1024 * N);           // 1 MB
    float* ksum = ctx + (size_t)B * HEADS * DH * DH;             // 16 KB
    unsigned short* w2 = (unsigned short*)(ksum + B * 512);      // 4 MB
    unsigned short* wqb = w2 + (size_t)B * D * D;                // 1.5 MB
    unsigned short* xT = wqb + (size_t)O3 * KDIM;                // 32 MB
    unsigned short* qT = xT + (size_t)B * N * KDIM;              // 32 MB

    // zero ctx + ksum (contiguous)
    hipMemsetAsync(ctx, 0, ((size_t)B * HEADS * DH * DH + B * 512) * sizeof(float), stream);

    prep<<<dim3(96, 8, B + 1), 256, 0, stream>>>(x, xT, w_qkv, wqb);

    gemm_qkv<<<dim3(N / 256, O3 / 256, B), 512, 0, stream>>>(wqb, xT, qT, kvb);

    context_mfma3<<<dim3(8, HEADS, B), 256, 0, stream>>>(kvb, ctx, ksum);
    fold_wout3<<<dim3(4, HEADS, B), 256, 0, stream>>>(w_out, ctx, ksum, w2);

    gemm_y_fused<<<dim3(N / 64, 1, B), 512, 0, stream>>>(w2, qT, b_out, g, out);
}